// Round 1
// baseline (397.793 us; speedup 1.0000x reference)
//
#include <hip/hip_runtime.h>

typedef unsigned short ushort_t;
typedef unsigned int   uint_t;

using bf16x8 = __attribute__((ext_vector_type(8))) short;
using f32x4  = __attribute__((ext_vector_type(4))) float;

#define BATCH 16
#define CIN   64
#define COUT  64
#define LSIG  16384
#define KW    128
#define LOUT  (LSIG - KW + 1)   /* 16257 */

#define NTILE 256                /* output positions per block */
#define ROWS  384                /* NTILE + 127 halo, rounded to 16 */

__device__ __forceinline__ ushort_t f2bf(float f) {
  union { float f; uint_t u; } v; v.f = f;
  uint_t r = v.u + 0x7fffu + ((v.u >> 16) & 1u);   // RNE, matches jnp f32->bf16
  return (ushort_t)(r >> 16);
}

// ---------------- pass 1: max|w| ----------------
__global__ void k_absmax(const float* __restrict__ w, uint_t* __restrict__ amax, int n) {
  int idx = blockIdx.x * blockDim.x + threadIdx.x;
  int stride = gridDim.x * blockDim.x;
  float m = 0.f;
  for (int i = idx; i < n; i += stride) m = fmaxf(m, fabsf(w[i]));
  for (int off = 32; off > 0; off >>= 1) m = fmaxf(m, __shfl_down(m, off, 64));
  if ((threadIdx.x & 63) == 0) atomicMax(amax, __float_as_uint(m)); // positive floats: uint order == float order
}

// ---------------- pass 2: quantize + reorder weights to Wt[k][o][i] (bf16 of integer) ----------------
__global__ void k_wprep(const float* __restrict__ w, const float* __restrict__ amaxp,
                        ushort_t* __restrict__ wt) {
  const float scale = amaxp[0] / 127.0f;
  const int o = blockIdx.x, i = blockIdx.y, k = threadIdx.x;
  const float q = rintf(w[((size_t)o * CIN + i) * KW + k] / scale); // integer in [-127,127], exact in bf16
  wt[((size_t)k * COUT + o) * CIN + i] = f2bf(q);
}

// ---------------- pass 3: signal -> sigT[b][n][i] bf16, i-block XOR-swizzled by (n&7) ----------------
__global__ void k_sprep(const float* __restrict__ sig, ushort_t* __restrict__ sigT) {
  __shared__ float tile[64][65];
  const int b = blockIdx.y;
  const int n0 = blockIdx.x * 64;
  const int t = threadIdx.x;
  {
    const int i = t >> 2, q = t & 3;
    const float4* src = (const float4*)(sig + ((size_t)(b * CIN + i)) * LSIG + n0 + q * 16);
    float4 v0 = src[0], v1 = src[1], v2 = src[2], v3 = src[3];
    float* trow = &tile[i][q * 16];
    trow[0]=v0.x; trow[1]=v0.y; trow[2]=v0.z;  trow[3]=v0.w;
    trow[4]=v1.x; trow[5]=v1.y; trow[6]=v1.z;  trow[7]=v1.w;
    trow[8]=v2.x; trow[9]=v2.y; trow[10]=v2.z; trow[11]=v2.w;
    trow[12]=v3.x; trow[13]=v3.y; trow[14]=v3.z; trow[15]=v3.w;
  }
  __syncthreads();
  const int nl = t & 63, cg = t >> 6;
  const int n = n0 + nl;
  uint_t wds[8];
#pragma unroll
  for (int p = 0; p < 8; ++p) {
    const int c0 = cg * 16 + 2 * p;
    const int c1 = c0 + 1;
    const int ia = (((c0 >> 3) ^ (n & 7)) << 3) | (c0 & 7);
    const int ib = (((c1 >> 3) ^ (n & 7)) << 3) | (c1 & 7);
    wds[p] = (uint_t)f2bf(tile[ia][nl]) | ((uint_t)f2bf(tile[ib][nl]) << 16);
  }
  uint4* dst = (uint4*)(sigT + ((size_t)b * LSIG + n) * CIN + cg * 16);
  dst[0] = make_uint4(wds[0], wds[1], wds[2], wds[3]);
  dst[1] = make_uint4(wds[4], wds[5], wds[6], wds[7]);
}

// ---------------- pass 4: the conv (implicit GEMM, MFMA) ----------------
// block: 128 threads = 2 waves; each wave owns 128 output positions x all 64 Cout.
// A-operand = weights (m = o), B-operand = signal (n = position), k-dim = Cin (2 halves of 32).
// K-loop: 128 taps x 2 halves, no barriers after the single staging sync.
#define CONV_STEP(S, AUSE, ALOAD, DO_LOAD) do {                                        \
    const int k_ = (S) >> 1, cs_ = (S) & 1;                                            \
    if (DO_LOAD) {                                                                     \
      const int sn_ = (S) + 1;                                                         \
      const ushort_t* p_ = wb + (size_t)(sn_ >> 1) * 4096 + (sn_ & 1) * 32;            \
      _Pragma("unroll") for (int of = 0; of < 4; ++of)                                 \
        ALOAD[of] = *(const bf16x8*)(p_ + of * 1024);                                  \
    }                                                                                  \
    const int r0_ = rowbase + k_;                                                      \
    const char* bp_ = (const char*)lds + r0_ * 128 + (((((cs_) << 2) | l4) ^ (r0_ & 7)) << 4); \
    bf16x8 B[8];                                                                       \
    _Pragma("unroll") for (int nf = 0; nf < 8; ++nf)                                   \
      B[nf] = *(const bf16x8*)(bp_ + nf * 2048);                                       \
    _Pragma("unroll") for (int of = 0; of < 4; ++of)                                   \
      _Pragma("unroll") for (int nf = 0; nf < 8; ++nf)                                 \
        acc[of][nf] = __builtin_amdgcn_mfma_f32_16x16x32_bf16(AUSE[of], B[nf], acc[of][nf], 0, 0, 0); \
  } while (0)

__global__ __launch_bounds__(128, 2) void k_conv(
    const ushort_t* __restrict__ sigT, const ushort_t* __restrict__ wt,
    const float* __restrict__ amaxp, const float* __restrict__ bias,
    float* __restrict__ out)
{
  __shared__ __align__(16) ushort_t lds[ROWS * CIN];   // 48 KB
  const int b  = blockIdx.y;
  const int n0 = blockIdx.x * NTILE;
  const int t  = threadIdx.x;
  const int wv = t >> 6;
  const int lane = t & 63;
  const int l15 = lane & 15, l4 = lane >> 4;

  // stage 384 rows x 128B = one contiguous 48KB span of sigT (clamped at buffer end;
  // overrun rows only feed store-masked outputs)
  {
    const uint4* srcall = (const uint4*)sigT;
    const size_t base = ((size_t)b * LSIG + n0) * 8;       // 8 uint4 per 128B row
    const size_t lim  = (size_t)BATCH * LSIG * 8;
    uint4* dst = (uint4*)lds;
    for (int c = t; c < ROWS * 8; c += 128) {
      size_t g = base + c;
      if (g >= lim) g = lim - 1;
      dst[c] = srcall[g];
    }
  }
  __syncthreads();

  f32x4 acc[4][8];
#pragma unroll
  for (int i = 0; i < 4; ++i)
#pragma unroll
    for (int j = 0; j < 8; ++j) acc[i][j] = (f32x4){0.f, 0.f, 0.f, 0.f};

  const ushort_t* wb = wt + l15 * CIN + l4 * 8;
  const int rowbase = wv * 128 + l15;

  bf16x8 A0[4], A1[4];
#pragma unroll
  for (int of = 0; of < 4; ++of) A0[of] = *(const bf16x8*)(wb + of * 1024);

  for (int s = 0; s < 256; s += 2) {
    CONV_STEP(s,     A0, A1, 1);
    CONV_STEP(s + 1, A1, A0, (s + 2 < 256));
  }

  const float sc = amaxp[0] / 127.0f;
#pragma unroll
  for (int of = 0; of < 4; ++of) {
#pragma unroll
    for (int nf = 0; nf < 8; ++nf) {
      const int n = n0 + wv * 128 + nf * 16 + l15;
      if (n < LOUT) {
#pragma unroll
        for (int r = 0; r < 4; ++r) {
          const int o = of * 16 + l4 * 4 + r;   // D row = (lane>>4)*4 + reg  [m89 layout]
          out[((size_t)b * COUT + o) * LOUT + n] = acc[of][nf][r] * sc + bias[o];
        }
      }
    }
  }
}

extern "C" void kernel_launch(void* const* d_in, const int* in_sizes, int n_in,
                              void* d_out, int out_size, void* d_ws, size_t ws_size,
                              hipStream_t stream) {
  const float* sig  = (const float*)d_in[0];
  const float* w    = (const float*)d_in[1];
  const float* bias = (const float*)d_in[2];
  float* out = (float*)d_out;

  // workspace layout: [0,4): amax bits | [4096, 4096+1MB): Wt | [2MB, 2MB+32MB): sigT (+16KB read slack)
  uint_t*   amax = (uint_t*)d_ws;
  ushort_t* wt   = (ushort_t*)((char*)d_ws + 4096);
  ushort_t* sigT = (ushort_t*)((char*)d_ws + (size_t)(2u << 20));

  hipMemsetAsync(d_ws, 0, 4, stream);
  hipLaunchKernelGGL(k_absmax, dim3(256), dim3(256), 0, stream, w, amax, COUT * CIN * KW);
  hipLaunchKernelGGL(k_wprep, dim3(COUT, CIN), dim3(KW), 0, stream, w, (const float*)amax, wt);
  hipLaunchKernelGGL(k_sprep, dim3(LSIG / 64, BATCH), dim3(256), 0, stream, sig, sigT);
  hipLaunchKernelGGL(k_conv, dim3((LOUT + NTILE - 1) / NTILE, BATCH), dim3(128), 0, stream,
                     sigT, wt, (const float*)amax, bias, out);
}

// Round 3
// 295.100 us; speedup vs baseline: 1.3480x; 1.3480x over previous
//
#include <hip/hip_runtime.h>

typedef unsigned short ushort_t;
typedef unsigned int   uint_t;

using bf16x8 = __attribute__((ext_vector_type(8))) short;
using f32x4  = __attribute__((ext_vector_type(4))) float;

#define BATCH 16
#define CIN   64
#define COUT  64
#define LSIG  16384
#define KW    128
#define LOUT  (LSIG - KW + 1)   /* 16257 */

#define NTILE 512                /* output positions per block */
#define ROWS  640                /* NTILE + 127 halo, rounded to 16 */

__device__ __forceinline__ ushort_t f2bf(float f) {
  union { float f; uint_t u; } v; v.f = f;
  uint_t r = v.u + 0x7fffu + ((v.u >> 16) & 1u);   // RNE, matches jnp f32->bf16
  return (ushort_t)(r >> 16);
}

// ---------------- pass 1: max|w| ----------------
__global__ void k_absmax(const float* __restrict__ w, uint_t* __restrict__ amax, int n) {
  int idx = blockIdx.x * blockDim.x + threadIdx.x;
  int stride = gridDim.x * blockDim.x;
  float m = 0.f;
  for (int i = idx; i < n; i += stride) m = fmaxf(m, fabsf(w[i]));
  for (int off = 32; off > 0; off >>= 1) m = fmaxf(m, __shfl_down(m, off, 64));
  if ((threadIdx.x & 63) == 0) atomicMax(amax, __float_as_uint(m)); // positive floats: uint order == float order
}

// ---------------- pass 2: quantize + reorder weights to Wt[k][o][i] (bf16 of integer) ----------------
__global__ void k_wprep(const float* __restrict__ w, const float* __restrict__ amaxp,
                        ushort_t* __restrict__ wt) {
  const float scale = amaxp[0] / 127.0f;
  const int o = blockIdx.x, i = blockIdx.y, k = threadIdx.x;
  const float q = rintf(w[((size_t)o * CIN + i) * KW + k] / scale); // integer in [-127,127], exact in bf16
  wt[((size_t)k * COUT + o) * CIN + i] = f2bf(q);
}

// ---------------- pass 3: signal -> sigT[b][n][i] bf16, i-block XOR-swizzled by (n&7) ----------------
__global__ void k_sprep(const float* __restrict__ sig, ushort_t* __restrict__ sigT) {
  __shared__ float tile[64][65];
  const int b = blockIdx.y;
  const int n0 = blockIdx.x * 64;
  const int t = threadIdx.x;
  {
    const int i = t >> 2, q = t & 3;
    const float4* src = (const float4*)(sig + ((size_t)(b * CIN + i)) * LSIG + n0 + q * 16);
    float4 v0 = src[0], v1 = src[1], v2 = src[2], v3 = src[3];
    float* trow = &tile[i][q * 16];
    trow[0]=v0.x; trow[1]=v0.y; trow[2]=v0.z;  trow[3]=v0.w;
    trow[4]=v1.x; trow[5]=v1.y; trow[6]=v1.z;  trow[7]=v1.w;
    trow[8]=v2.x; trow[9]=v2.y; trow[10]=v2.z; trow[11]=v2.w;
    trow[12]=v3.x; trow[13]=v3.y; trow[14]=v3.z; trow[15]=v3.w;
  }
  __syncthreads();
  const int nl = t & 63, cg = t >> 6;
  const int n = n0 + nl;
  uint_t wds[8];
#pragma unroll
  for (int p = 0; p < 8; ++p) {
    const int c0 = cg * 16 + 2 * p;
    const int c1 = c0 + 1;
    const int ia = (((c0 >> 3) ^ (n & 7)) << 3) | (c0 & 7);
    const int ib = (((c1 >> 3) ^ (n & 7)) << 3) | (c1 & 7);
    wds[p] = (uint_t)f2bf(tile[ia][nl]) | ((uint_t)f2bf(tile[ib][nl]) << 16);
  }
  uint4* dst = (uint4*)(sigT + ((size_t)b * LSIG + n) * CIN + cg * 16);
  dst[0] = make_uint4(wds[0], wds[1], wds[2], wds[3]);
  dst[1] = make_uint4(wds[4], wds[5], wds[6], wds[7]);
}

// ---------------- pass 4: the conv (implicit GEMM, MFMA) ----------------
// block: 256 threads = 4 waves; each wave owns 128 output positions x all 64 Cout.
// grid = 32 x 16 = 512 blocks = exactly 2 blocks/CU (2x80KB LDS = 160KB exact fit),
// 8 waves/CU -> 2 waves/SIMD steady-state, no tail.
// A-operand = weights (m = o), B-operand = signal (n = position), k-dim = Cin (2 halves of 32).
// K-loop: 128 taps x 2 halves, no barriers after the single staging sync.
#define CONV_STEP(S, AUSE, ALOAD, DO_LOAD) do {                                        \
    const int k_ = (S) >> 1, cs_ = (S) & 1;                                            \
    if (DO_LOAD) {                                                                     \
      const int sn_ = (S) + 1;                                                         \
      const ushort_t* p_ = wb + (size_t)(sn_ >> 1) * 4096 + (sn_ & 1) * 32;            \
      _Pragma("unroll") for (int of = 0; of < 4; ++of)                                 \
        ALOAD[of] = *(const bf16x8*)(p_ + of * 1024);                                  \
    }                                                                                  \
    const int r0_ = rowbase + k_;                                                      \
    const char* bp_ = (const char*)lds + r0_ * 128 + (((((cs_) << 2) | l4) ^ (r0_ & 7)) << 4); \
    bf16x8 B[8];                                                                       \
    _Pragma("unroll") for (int nf = 0; nf < 8; ++nf)                                   \
      B[nf] = *(const bf16x8*)(bp_ + nf * 2048);                                       \
    _Pragma("unroll") for (int of = 0; of < 4; ++of)                                   \
      _Pragma("unroll") for (int nf = 0; nf < 8; ++nf)                                 \
        acc[of][nf] = __builtin_amdgcn_mfma_f32_16x16x32_bf16(AUSE[of], B[nf], acc[of][nf], 0, 0, 0); \
  } while (0)

__global__ __launch_bounds__(256, 2) void k_conv(
    const ushort_t* __restrict__ sigT, const ushort_t* __restrict__ wt,
    const float* __restrict__ amaxp, const float* __restrict__ bias,
    float* __restrict__ out)
{
  __shared__ __align__(16) ushort_t lds[ROWS * CIN];   // 80 KB
  const int b  = blockIdx.y;
  const int n0 = blockIdx.x * NTILE;
  const int t  = threadIdx.x;
  const int wv = t >> 6;
  const int lane = t & 63;
  const int l15 = lane & 15, l4 = lane >> 4;

  // stage 640 rows x 128B = one contiguous 80KB span of sigT (clamped at buffer end;
  // overrun rows only feed store-masked outputs)
  {
    const uint4* srcall = (const uint4*)sigT;
    const size_t base = ((size_t)b * LSIG + n0) * 8;       // 8 uint4 per 128B row
    const size_t lim  = (size_t)BATCH * LSIG * 8;
    uint4* dst = (uint4*)lds;
    for (int c = t; c < ROWS * 8; c += 256) {
      size_t g = base + c;
      if (g >= lim) g = lim - 1;
      dst[c] = srcall[g];
    }
  }
  __syncthreads();

  f32x4 acc[4][8];
#pragma unroll
  for (int i = 0; i < 4; ++i)
#pragma unroll
    for (int j = 0; j < 8; ++j) acc[i][j] = (f32x4){0.f, 0.f, 0.f, 0.f};

  const ushort_t* wb = wt + l15 * CIN + l4 * 8;
  const int rowbase = wv * 128 + l15;

  bf16x8 A0[4], A1[4];
#pragma unroll
  for (int of = 0; of < 4; ++of) A0[of] = *(const bf16x8*)(wb + of * 1024);

  for (int s = 0; s < 256; s += 2) {
    CONV_STEP(s,     A0, A1, 1);
    CONV_STEP(s + 1, A1, A0, (s + 2 < 256));
  }

  const float sc = amaxp[0] / 127.0f;
#pragma unroll
  for (int of = 0; of < 4; ++of) {
#pragma unroll
    for (int nf = 0; nf < 8; ++nf) {
      const int n = n0 + wv * 128 + nf * 16 + l15;
      if (n < LOUT) {
#pragma unroll
        for (int r = 0; r < 4; ++r) {
          const int o = of * 16 + l4 * 4 + r;   // D row = (lane>>4)*4 + reg  [m89 layout]
          out[((size_t)b * COUT + o) * LOUT + n] = acc[of][nf][r] * sc + bias[o];
        }
      }
    }
  }
}

extern "C" void kernel_launch(void* const* d_in, const int* in_sizes, int n_in,
                              void* d_out, int out_size, void* d_ws, size_t ws_size,
                              hipStream_t stream) {
  const float* sig  = (const float*)d_in[0];
  const float* w    = (const float*)d_in[1];
  const float* bias = (const float*)d_in[2];
  float* out = (float*)d_out;

  // workspace layout: [0,4): amax bits | [4096, 4096+1MB): Wt | [2MB, 2MB+32MB): sigT (+16KB read slack)
  uint_t*   amax = (uint_t*)d_ws;
  ushort_t* wt   = (ushort_t*)((char*)d_ws + 4096);
  ushort_t* sigT = (ushort_t*)((char*)d_ws + (size_t)(2u << 20));

  hipMemsetAsync(d_ws, 0, 4, stream);
  hipLaunchKernelGGL(k_absmax, dim3(256), dim3(256), 0, stream, w, amax, COUT * CIN * KW);
  hipLaunchKernelGGL(k_wprep, dim3(COUT, CIN), dim3(KW), 0, stream, w, (const float*)amax, wt);
  hipLaunchKernelGGL(k_sprep, dim3(LSIG / 64, BATCH), dim3(256), 0, stream, sig, sigT);
  hipLaunchKernelGGL(k_conv, dim3((LOUT + NTILE - 1) / NTILE, BATCH), dim3(256), 0, stream,
                     sigT, wt, (const float*)amax, bias, out);
}

// Round 4
// 294.954 us; speedup vs baseline: 1.3487x; 1.0005x over previous
//
#include <hip/hip_runtime.h>

typedef unsigned short ushort_t;
typedef unsigned int   uint_t;

using bf16x8 = __attribute__((ext_vector_type(8))) short;
using f32x4  = __attribute__((ext_vector_type(4))) float;

#define BATCH 16
#define CIN   64
#define COUT  64
#define LSIG  16384
#define KW    128
#define LOUT  (LSIG - KW + 1)   /* 16257 */

#define NTILE 512                /* output positions per block */
#define ROWS  640                /* NTILE + 127 halo, rounded to 16 */

__device__ __forceinline__ ushort_t f2bf(float f) {
  union { float f; uint_t u; } v; v.f = f;
  uint_t r = v.u + 0x7fffu + ((v.u >> 16) & 1u);   // RNE, matches jnp f32->bf16
  return (ushort_t)(r >> 16);
}

// ---------------- pass 1: max|w| ----------------
__global__ void k_absmax(const float* __restrict__ w, uint_t* __restrict__ amax, int n) {
  int idx = blockIdx.x * blockDim.x + threadIdx.x;
  int stride = gridDim.x * blockDim.x;
  float m = 0.f;
  for (int i = idx; i < n; i += stride) m = fmaxf(m, fabsf(w[i]));
  for (int off = 32; off > 0; off >>= 1) m = fmaxf(m, __shfl_down(m, off, 64));
  if ((threadIdx.x & 63) == 0) atomicMax(amax, __float_as_uint(m)); // positive floats: uint order == float order
}

// ---------------- pass 2: quantize + reorder weights to Wt[k][o][i] (bf16 of integer) ----------------
__global__ void k_wprep(const float* __restrict__ w, const float* __restrict__ amaxp,
                        ushort_t* __restrict__ wt) {
  const float scale = amaxp[0] / 127.0f;
  const int o = blockIdx.x, i = blockIdx.y, k = threadIdx.x;
  const float q = rintf(w[((size_t)o * CIN + i) * KW + k] / scale); // integer in [-127,127], exact in bf16
  wt[((size_t)k * COUT + o) * CIN + i] = f2bf(q);
}

// ---------------- pass 3: signal -> sigT[b][n][i] bf16, i-block XOR-swizzled by (n&7) ----------------
__global__ void k_sprep(const float* __restrict__ sig, ushort_t* __restrict__ sigT) {
  __shared__ float tile[64][65];
  const int b = blockIdx.y;
  const int n0 = blockIdx.x * 64;
  const int t = threadIdx.x;
  {
    const int i = t >> 2, q = t & 3;
    const float4* src = (const float4*)(sig + ((size_t)(b * CIN + i)) * LSIG + n0 + q * 16);
    float4 v0 = src[0], v1 = src[1], v2 = src[2], v3 = src[3];
    float* trow = &tile[i][q * 16];
    trow[0]=v0.x; trow[1]=v0.y; trow[2]=v0.z;  trow[3]=v0.w;
    trow[4]=v1.x; trow[5]=v1.y; trow[6]=v1.z;  trow[7]=v1.w;
    trow[8]=v2.x; trow[9]=v2.y; trow[10]=v2.z; trow[11]=v2.w;
    trow[12]=v3.x; trow[13]=v3.y; trow[14]=v3.z; trow[15]=v3.w;
  }
  __syncthreads();
  const int nl = t & 63, cg = t >> 6;
  const int n = n0 + nl;
  uint_t wds[8];
#pragma unroll
  for (int p = 0; p < 8; ++p) {
    const int c0 = cg * 16 + 2 * p;
    const int c1 = c0 + 1;
    const int ia = (((c0 >> 3) ^ (n & 7)) << 3) | (c0 & 7);
    const int ib = (((c1 >> 3) ^ (n & 7)) << 3) | (c1 & 7);
    wds[p] = (uint_t)f2bf(tile[ia][nl]) | ((uint_t)f2bf(tile[ib][nl]) << 16);
  }
  uint4* dst = (uint4*)(sigT + ((size_t)b * LSIG + n) * CIN + cg * 16);
  dst[0] = make_uint4(wds[0], wds[1], wds[2], wds[3]);
  dst[1] = make_uint4(wds[4], wds[5], wds[6], wds[7]);
}

// ---------------- pass 4: the conv (implicit GEMM, MFMA) ----------------
// block: 256 threads = 4 waves; each wave owns 128 output positions x all 64 Cout.
// grid = 32 x 16 = 512 blocks = exactly 2 blocks/CU (2x80KB LDS = 160KB exact fit),
// 8 waves/CU -> 2 waves/SIMD steady-state, no tail.
// A-operand = weights (m = o), B-operand = signal (n = position), k-dim = Cin (2 halves of 32).
// K-loop: 128 taps x 2 halves; BOTH A (global/L2) and B (LDS) are software-pipelined
// one step ahead so the lgkmcnt/vmcnt waits land after a full MFMA cluster.
#define CONV_STEP(S, AUSE, ALOAD, BUSE, BLOAD, DO_ALOAD, DO_BLOAD) do {                \
    if (DO_ALOAD) {                                                                    \
      const int sn_ = (S) + 1;                                                         \
      const ushort_t* p_ = wb + (size_t)(sn_ >> 1) * 4096 + (sn_ & 1) * 32;            \
      _Pragma("unroll") for (int of = 0; of < 4; ++of)                                 \
        ALOAD[of] = *(const bf16x8*)(p_ + of * 1024);                                  \
    }                                                                                  \
    if (DO_BLOAD) {                                                                    \
      const int sb_ = (S) + 1;                                                         \
      const int kb_ = sb_ >> 1, cb_ = sb_ & 1;                                         \
      const int rb_ = rowbase + kb_;                                                   \
      const char* bpn_ = (const char*)lds + rb_ * 128 + (((((cb_) << 2) | l4) ^ (rb_ & 7)) << 4); \
      _Pragma("unroll") for (int nf = 0; nf < 8; ++nf)                                 \
        BLOAD[nf] = *(const bf16x8*)(bpn_ + nf * 2048);                                \
    }                                                                                  \
    _Pragma("unroll") for (int of = 0; of < 4; ++of)                                   \
      _Pragma("unroll") for (int nf = 0; nf < 8; ++nf)                                 \
        acc[of][nf] = __builtin_amdgcn_mfma_f32_16x16x32_bf16(AUSE[of], BUSE[nf], acc[of][nf], 0, 0, 0); \
  } while (0)

__global__ __launch_bounds__(256, 2) void k_conv(
    const ushort_t* __restrict__ sigT, const ushort_t* __restrict__ wt,
    const float* __restrict__ amaxp, const float* __restrict__ bias,
    float* __restrict__ out)
{
  __shared__ __align__(16) ushort_t lds[ROWS * CIN];   // 80 KB
  const int b  = blockIdx.y;
  const int n0 = blockIdx.x * NTILE;
  const int t  = threadIdx.x;
  const int wv = t >> 6;
  const int lane = t & 63;
  const int l15 = lane & 15, l4 = lane >> 4;

  // stage 640 rows x 128B = one contiguous 80KB span of sigT (clamped at buffer end;
  // overrun rows only feed store-masked outputs)
  {
    const uint4* srcall = (const uint4*)sigT;
    const size_t base = ((size_t)b * LSIG + n0) * 8;       // 8 uint4 per 128B row
    const size_t lim  = (size_t)BATCH * LSIG * 8;
    uint4* dst = (uint4*)lds;
    for (int c = t; c < ROWS * 8; c += 256) {
      size_t g = base + c;
      if (g >= lim) g = lim - 1;
      dst[c] = srcall[g];
    }
  }
  __syncthreads();

  f32x4 acc[4][8];
#pragma unroll
  for (int i = 0; i < 4; ++i)
#pragma unroll
    for (int j = 0; j < 8; ++j) acc[i][j] = (f32x4){0.f, 0.f, 0.f, 0.f};

  const ushort_t* wb = wt + l15 * CIN + l4 * 8;
  const int rowbase = wv * 128 + l15;

  bf16x8 A0[4], A1[4], B0[8], B1[8];
#pragma unroll
  for (int of = 0; of < 4; ++of) A0[of] = *(const bf16x8*)(wb + of * 1024);
  {
    // prologue: B for step 0 (k=0, cs=0)
    const char* bp0 = (const char*)lds + rowbase * 128 + (((l4) ^ (rowbase & 7)) << 4);
#pragma unroll
    for (int nf = 0; nf < 8; ++nf) B0[nf] = *(const bf16x8*)(bp0 + nf * 2048);
  }

  for (int s = 0; s < 256; s += 2) {
    CONV_STEP(s,     A0, A1, B0, B1, 1, 1);
    CONV_STEP(s + 1, A1, A0, B1, B0, (s + 2 < 256), (s + 2 < 256));
  }

  const float sc = amaxp[0] / 127.0f;
#pragma unroll
  for (int of = 0; of < 4; ++of) {
#pragma unroll
    for (int nf = 0; nf < 8; ++nf) {
      const int n = n0 + wv * 128 + nf * 16 + l15;
      if (n < LOUT) {
#pragma unroll
        for (int r = 0; r < 4; ++r) {
          const int o = of * 16 + l4 * 4 + r;   // D row = (lane>>4)*4 + reg  [m89 layout]
          out[((size_t)b * COUT + o) * LOUT + n] = acc[of][nf][r] * sc + bias[o];
        }
      }
    }
  }
}

extern "C" void kernel_launch(void* const* d_in, const int* in_sizes, int n_in,
                              void* d_out, int out_size, void* d_ws, size_t ws_size,
                              hipStream_t stream) {
  const float* sig  = (const float*)d_in[0];
  const float* w    = (const float*)d_in[1];
  const float* bias = (const float*)d_in[2];
  float* out = (float*)d_out;

  // workspace layout: [0,4): amax bits | [4096, 4096+1MB): Wt | [2MB, 2MB+32MB): sigT (+16KB read slack)
  uint_t*   amax = (uint_t*)d_ws;
  ushort_t* wt   = (ushort_t*)((char*)d_ws + 4096);
  ushort_t* sigT = (ushort_t*)((char*)d_ws + (size_t)(2u << 20));

  hipMemsetAsync(d_ws, 0, 4, stream);
  hipLaunchKernelGGL(k_absmax, dim3(256), dim3(256), 0, stream, w, amax, COUT * CIN * KW);
  hipLaunchKernelGGL(k_wprep, dim3(COUT, CIN), dim3(KW), 0, stream, w, (const float*)amax, wt);
  hipLaunchKernelGGL(k_sprep, dim3(LSIG / 64, BATCH), dim3(256), 0, stream, sig, sigT);
  hipLaunchKernelGGL(k_conv, dim3((LOUT + NTILE - 1) / NTILE, BATCH), dim3(256), 0, stream,
                     sigT, wt, (const float*)amax, bias, out);
}